// Round 3
// baseline (587.530 us; speedup 1.0000x reference)
//
#include <hip/hip_runtime.h>
#include <hip/hip_cooperative_groups.h>
#include <math.h>

namespace cg = cooperative_groups;

#define N_IMG 32
#define N_ATOM 400000
#define NE (N_ATOM*3)        // 1,200,000 floats per image row
#define NE4 (NE/4)           // 300,000 float4 per image row
#define KMAXC 0.1f
#define DLTKC 0.02f
#define EPSE 0.1f

#define NSUM 151
#define OFF_SDD 0    // 31 per-link |d|^2
#define OFF_SPM 31   // 30 d[j-1].d[j]
#define OFF_SFP 61   // 30 f[j].d[j-1]
#define OFF_SFM 91   // 30 f[j].d[j]
#define OFF_SFF 121  // 30 |f[j]|^2

#define NCHUNK 5     // 5 chunks x 6 interior images = images 1..30
#define MAXBLK 2040  // <= 2048 co-resident (8 blk/CU x 256 CU), multiple of 5

__device__ __forceinline__ float dot4(float4 a, float4 b) {
    return a.x*b.x + a.y*b.y + a.z*b.z + a.w*b.w;
}
__device__ __forceinline__ float4 sub4(float4 a, float4 b) {
    return make_float4(a.x-b.x, a.y-b.y, a.z-b.z, a.w-b.w);
}

// Full-wave (64-lane) sum via DPP on the VALU pipe. Lane 63 has the total.
__device__ __forceinline__ float wred_dpp(float x) {
    x += __int_as_float(__builtin_amdgcn_update_dpp(0, __float_as_int(x), 0x111, 0xf, 0xf, false)); // row_shr:1
    x += __int_as_float(__builtin_amdgcn_update_dpp(0, __float_as_int(x), 0x112, 0xf, 0xf, false)); // row_shr:2
    x += __int_as_float(__builtin_amdgcn_update_dpp(0, __float_as_int(x), 0x114, 0xf, 0xf, false)); // row_shr:4
    x += __int_as_float(__builtin_amdgcn_update_dpp(0, __float_as_int(x), 0x118, 0xf, 0xf, false)); // row_shr:8
    x += __int_as_float(__builtin_amdgcn_update_dpp(0, __float_as_int(x), 0x142, 0xa, 0xf, false)); // row_bcast:15
    x += __int_as_float(__builtin_amdgcn_update_dpp(0, __float_as_int(x), 0x143, 0xc, 0xf, false)); // row_bcast:31
    return x;
}

// ONE cooperative kernel replacing pass1 + reduce + coeff + pass2.
// R2 showed: sum of kernel durations ~230us but harness measures ~420us —
// the gap is inter-kernel launch/serialization overhead of 4 dependent
// launches. Fusing removes 3 launches; grid.sync() replaces the kernel
// boundaries. Block b owns chunk c=b%5 and grid-strides columns with
// stride xstride=gridDim.x/5 (phase-1 accumulators stay per-chunk scalars).
__global__ __launch_bounds__(256) void eb_fused(const float* __restrict__ pos,
                                                const float* __restrict__ frc,
                                                const float* __restrict__ eng,
                                                float* __restrict__ out,
                                                float* __restrict__ sums,
                                                int xstride) {
    cg::grid_group gg = cg::this_grid();
    const int b = blockIdx.x;
    const int c = b % NCHUNK;
    const int xb = b / NCHUNK;
    const int j0 = 1 + 6 * c;
    const float4* pos4 = reinterpret_cast<const float4*>(pos);
    const float4* frc4 = reinterpret_cast<const float4*>(frc);

    // ---- zero the global accumulators (ws persists across launches) ----
    if (b == 0 && threadIdx.x < NSUM) sums[threadIdx.x] = 0.f;
    gg.sync();

    // ---- phase 1: per-chunk dot-product sums ----
    float sdd[7], spm[6], sfp[6], sfm[6], sff[6];
#pragma unroll
    for (int i = 0; i < 7; ++i) sdd[i] = 0.f;
#pragma unroll
    for (int i = 0; i < 6; ++i) { spm[i] = 0.f; sfp[i] = 0.f; sfm[i] = 0.f; sff[i] = 0.f; }

    for (int t = xb * 256 + threadIdx.x; t < NE4; t += xstride * 256) {
        float4 p[8], f[6];
#pragma unroll
        for (int i = 0; i < 8; ++i) p[i] = pos4[(size_t)(j0 - 1 + i) * NE4 + t];
#pragma unroll
        for (int i = 0; i < 6; ++i) f[i] = frc4[(size_t)(j0 + i) * NE4 + t];
        float4 d[7];
#pragma unroll
        for (int i = 0; i < 7; ++i) d[i] = sub4(p[i + 1], p[i]);   // d[i] = link (j0-1+i)
#pragma unroll
        for (int i = 0; i < 7; ++i) sdd[i] += dot4(d[i], d[i]);
#pragma unroll
        for (int jj = 0; jj < 6; ++jj) {
            spm[jj] += dot4(d[jj], d[jj + 1]);   // d[j-1].d[j]
            sfp[jj] += dot4(f[jj], d[jj]);       // f.d[j-1]
            sfm[jj] += dot4(f[jj], d[jj + 1]);   // f.d[j]
            sff[jj] += dot4(f[jj], f[jj]);
        }
    }

    float v[31];
#pragma unroll
    for (int i = 0; i < 7; ++i) v[i] = sdd[i];
#pragma unroll
    for (int i = 0; i < 6; ++i) { v[7 + i] = spm[i]; v[13 + i] = sfp[i]; v[19 + i] = sfm[i]; v[25 + i] = sff[i]; }

    __shared__ float red[4][31];
    {
        const int wave = threadIdx.x >> 6;
        const int lane = threadIdx.x & 63;
#pragma unroll
        for (int s = 0; s < 31; ++s) {
            float r = wred_dpp(v[s]);
            if (lane == 63) red[wave][s] = r;
        }
    }
    __syncthreads();
    {
        const int s = threadIdx.x;
        if (s < 31) {
            float r = red[0][s] + red[1][s] + red[2][s] + red[3][s];
            int slot; bool owned = true;
            if (s < 7)       { owned = (s < 6) || (c == NCHUNK - 1); slot = OFF_SDD + (j0 - 1) + s; }
            else if (s < 13) slot = OFF_SPM + (j0 - 1) + (s - 7);
            else if (s < 19) slot = OFF_SFP + (j0 - 1) + (s - 13);
            else if (s < 25) slot = OFF_SFM + (j0 - 1) + (s - 19);
            else             slot = OFF_SFF + (j0 - 1) + (s - 25);
            if (owned) atomicAdd(&sums[slot], r);   // ~xstride adds per address
        }
    }
    __threadfence();
    gg.sync();

    // ---- coeff: every block computes A/B/C redundantly into LDS ----
    __shared__ float Ac[30], Bc[30], Cc[30];
    if (threadIdx.x < 30) {
        const int jj = threadIdx.x;
        volatile const float* vs = sums;   // bypass L1: sums written via atomics
        float e[N_IMG];
        float emin = 1e30f, emax = -1e30f;
        int imax = 0;
        for (int i = 0; i < N_IMG; ++i) {
            float vv = eng[i];
            e[i] = vv;
            if (vv < emin) emin = vv;
            if (vv > emax) { emax = vv; imax = i; }
        }
        const float eref = emin - EPSE;
        float e0 = e[jj], e1 = e[jj + 1], e2 = e[jj + 2];
        float eim = fmaxf(e1, e0);
        float km = KMAXC - DLTKC * (emax - eim) / (emax - eref);
        if (eim < eref) km = KMAXC - DLTKC;
        float eip = fmaxf(e2, e1);
        float kp = KMAXC - DLTKC * (emax - eip) / (emax - eref);
        if (eip < eref) kp = KMAXC - DLTKC;

        float pp = (e2 > e1 && e1 > e0) ? 1.f : 0.f;
        float mm = (e2 < e1 && e1 < e0) ? 1.f : 0.f;
        float nb = 1.f - fmaxf(pp, mm);
        float mp = ((e2 > e1) ? 1.f : 0.f) * nb;
        float mq = ((e2 < e1) ? 1.f : 0.f) * nb;
        float dvmax = fmaxf(fabsf(e2 - e1), fabsf(e0 - e1));
        float dvmin = fminf(fabsf(e2 - e1), fabsf(e0 - e1));
        float a = pp + dvmax * mp + dvmin * mq;   // coeff of tau_p
        float bb = mm + dvmin * mp + dvmax * mq;  // coeff of tau_m
        float Spp = vs[OFF_SDD + jj];
        float Smm = vs[OFF_SDD + jj + 1];
        float Spm = vs[OFF_SPM + jj];
        float Sfp = vs[OFF_SFP + jj];
        float Sfm = vs[OFF_SFM + jj];
        float Sff = vs[OFF_SFF + jj];
        float ntau2 = a * a * Spp + 2.f * a * bb * Spm + bb * bb * Smm;
        float ntau = sqrtf(ntau2);
        float ta = a / ntau, tb = bb / ntau;
        float fpar = ta * Sfp + tb * Sfm;                       // dot(frc, tau)
        float spar = kp * sqrtf(Smm) - km * sqrtf(Spp);         // spr_para magnitude
        float ffpp = Sff - fpar * fpar;                         // |frc_perp|^2
        float strau = ta * (kp * Spm - km * Spp) + tb * (kp * Smm - km * Spm); // dot(spr,tau)
        float Sss = kp * kp * Smm - 2.f * kp * km * Spm + km * km * Spp;       // dot(spr,spr)
        float sspp = Sss - 2.f * spar * strau + spar * spar;    // |spr_perp|^2
        float Ssf = kp * Sfm - km * Sfp;                        // dot(spr,frc)
        float spfp = Ssf - fpar * strau;                        // dot(spr_perp,frc_perp)
        float sw = (2.0f / 3.14159265358979323846f) * atan2f(ffpp, sspp);
        float cc = spfp * sw;
        float g = (jj == imax) ? 2.f : 1.f;                     // .at[i_raw].multiply(2.0)
        float w = (cc - g) * fpar / ntau;
        Ac[jj] = 1.f - cc;       // A: coeff of frc
        Bc[jj] = kp + w * bb;    // B: coeff of tau_m (=d[j])
        Cc[jj] = w * a - km;     // C: coeff of tau_p (=d[j-1])
    }
    __syncthreads();

    // ---- phase 2: write output rows j0..j0+5 (+ edge rows) ----
    float4* out4 = reinterpret_cast<float4*>(out);
    for (int t = xb * 256 + threadIdx.x; t < NE4; t += xstride * 256) {
        float4 p[8], f[6];
#pragma unroll
        for (int i = 0; i < 8; ++i) p[i] = pos4[(size_t)(j0 - 1 + i) * NE4 + t];
#pragma unroll
        for (int i = 0; i < 6; ++i) f[i] = frc4[(size_t)(j0 + i) * NE4 + t];

        if (c == 0) out4[t] = frc4[t];                                   // out[0]=frc[0]
        if (c == NCHUNK - 1) {
            size_t i31 = (size_t)31 * NE4 + t;
            out4[i31] = frc4[i31];                                       // out[31]=frc[31]
        }

        float4 d[7];
#pragma unroll
        for (int i = 0; i < 7; ++i) d[i] = sub4(p[i + 1], p[i]);
#pragma unroll
        for (int jj = 0; jj < 6; ++jj) {
            const int g = j0 + jj - 1;
            float ca = Ac[g], cb = Bc[g], cd = Cc[g];
            float4 o;
            o.x = ca * f[jj].x + cb * d[jj + 1].x + cd * d[jj].x;
            o.y = ca * f[jj].y + cb * d[jj + 1].y + cd * d[jj].y;
            o.z = ca * f[jj].z + cb * d[jj + 1].z + cd * d[jj].z;
            o.w = ca * f[jj].w + cb * d[jj + 1].w + cd * d[jj].w;
            out4[(size_t)(j0 + jj) * NE4 + t] = o;
        }
    }
}

extern "C" void kernel_launch(void* const* d_in, const int* in_sizes, int n_in,
                              void* d_out, int out_size, void* d_ws, size_t ws_size,
                              hipStream_t stream) {
    const float* pos = (const float*)d_in[0];
    const float* frc = (const float*)d_in[1];
    const float* eng = (const float*)d_in[2];
    float* out = (float*)d_out;
    float* sums = (float*)d_ws;       // [0..150]

    // co-resident grid sizing (cached): blocks/CU from occupancy API x 256 CUs
    static int nblk = 0;
    if (nblk == 0) {
        int perCU = 0;
        hipOccupancyMaxActiveBlocksPerMultiprocessor(&perCU, (const void*)eb_fused, 256, 0);
        if (perCU < 1) perCU = 1;
        long cap = (long)perCU * 256;          // MI355X: 256 CUs
        if (cap > MAXBLK) cap = MAXBLK;
        nblk = (int)(cap / NCHUNK) * NCHUNK;   // multiple of 5
        if (nblk < NCHUNK) nblk = NCHUNK;
    }
    int xstride = nblk / NCHUNK;

    void* args[] = { (void*)&pos, (void*)&frc, (void*)&eng,
                     (void*)&out, (void*)&sums, (void*)&xstride };
    hipLaunchCooperativeKernel((const void*)eb_fused, dim3(nblk), dim3(256),
                               args, 0, stream);
}